// Round 6
// baseline (370.368 us; speedup 1.0000x reference)
//
#include <hip/hip_runtime.h>
#include <stdint.h>

#define M_ROWS 65536
#define C_DIM  256
#define K_CLS  20
#define P_POS  2048
#define MARGIN_F 0.3f
#define EPS_D (0.0001f / 256.0f)

typedef short  short8  __attribute__((ext_vector_type(8)));
typedef float  floatx4 __attribute__((ext_vector_type(4)));

__device__ __forceinline__ unsigned short f2bf(float x) {
    uint32_t u = __float_as_uint(x);
    u += 0x7fffu + ((u >> 16) & 1u);   // RNE
    return (unsigned short)(u >> 16);
}
__device__ __forceinline__ float bf2f(unsigned short h) {
    return __uint_as_float(((uint32_t)h) << 16);
}

// async 16B/lane global -> LDS (wave-uniform LDS base + lane*16)
__device__ __forceinline__ void async_copy16(const void* g, void* l) {
    __builtin_amdgcn_global_load_lds(
        (const __attribute__((address_space(1))) void*)g,
        (__attribute__((address_space(3))) void*)l, 16, 0, 0);
}

// ------- Kernel 1: sigmoid -> bf16 + fp32 row norms (+ zero the loss acc) ---
__global__ __launch_bounds__(256) void sigmoid_norm_k(
        const float* __restrict__ feat,
        unsigned short* __restrict__ Sb,
        float* __restrict__ xx,
        float* __restrict__ out) {
    if (blockIdx.x == 0 && threadIdx.x == 0) out[0] = 0.f;  // loss_k accumulates later (stream-ordered)
    const int wave = threadIdx.x >> 6, lane = threadIdx.x & 63;
    const int row = blockIdx.x * 4 + wave;
    const float4 v = *(const float4*)(feat + (size_t)row * C_DIM + lane * 4);

    unsigned short b0 = f2bf(1.f / (1.f + __expf(-v.x)));
    unsigned short b1 = f2bf(1.f / (1.f + __expf(-v.y)));
    unsigned short b2 = f2bf(1.f / (1.f + __expf(-v.z)));
    unsigned short b3 = f2bf(1.f / (1.f + __expf(-v.w)));

    ushort4 st; st.x = b0; st.y = b1; st.z = b2; st.w = b3;
    *(ushort4*)(Sb + (size_t)row * C_DIM + lane * 4) = st;

    float s0 = bf2f(b0), s1 = bf2f(b1), s2 = bf2f(b2), s3 = bf2f(b3);
    float sum = s0 * s0 + s1 * s1 + s2 * s2 + s3 * s3;
#pragma unroll
    for (int off = 32; off; off >>= 1) sum += __shfl_down(sum, off);
    if (lane == 0) xx[row] = sum;
}

// ---------------- Kernel 2: fused distance-GEMM + arg-select ----------------
// Block 128i x 32j, TWO waves stacked in i; wave tile 64i x 32j: A (64 x 256)
// in 128 VGPRs -> each B fragment read feeds 4 MFMAs (2x less LDS traffic per
// FLOP than R5's 32x32 wave tile). B double-buffered 2 x 16 KB via
// global_load_lds w/ XOR swizzle in the global source address. yy pipelined
// in registers. Arg-select: enc = (bits(yy-2*x.y) & ~2047) | j, single
// v_min/v_max. Grid 640 = 16 i-blk x 40 (k,type); bid%8 -> same XCD per
// (k,type) so the 1MB B-set is L2-resident. launch_bounds(128,2): VGPR<=256,
// 4 blocks/CU capacity -> all 640 blocks co-resident.
__global__ __launch_bounds__(128, 2) void select_k(
        const unsigned short* __restrict__ Sb,
        const float* __restrict__ xx,
        const int* __restrict__ pos_idx,
        const int* __restrict__ neg_idx,
        int* __restrict__ hp,
        int* __restrict__ hn) {
    __shared__ __align__(16) unsigned char Bt[2][32 * 512];   // 32 KiB

    const int tid    = threadIdx.x;
    const int w      = tid >> 6;        // 0..1
    const int lane   = tid & 63;
    const int lane15 = lane & 15;
    const int quad   = lane >> 4;
    const int hi5    = lane >> 5;       // staging sub-row

    const int bid    = blockIdx.x;      // 640 = 16 i-blocks x 40 (k,type)
    const int ctid   = bid % 40;        // same ctid -> same XCD (mod-8)
    const int i_blk  = bid / 40;
    const int k      = ctid >> 1;
    const int isNeg  = ctid & 1;
    const int i0     = i_blk * 128;

    const int* __restrict__ idxA = pos_idx + k * P_POS;
    const int* __restrict__ idxB = (isNeg ? neg_idx : pos_idx) + k * P_POS;
    int*       outIdx            = (isNeg ? hn : hp) + k * P_POS;

    const char* SbB = (const char*)Sb;          // row stride 512 B

    // ---- per-lane staging offsets: 2 waves x 8 copies cover 32 rows ----
    // copy c: rows w*16 + c*2 + hi5 ; global unit = (lane&31) ^ (row&7)
    int goff[8];
#pragma unroll
    for (int c = 0; c < 8; ++c)
        goff[c] = ((lane & 31) ^ ((c * 2 + hi5) & 7)) << 4;
    const int strow = w * 16 + hi5;     // + c*2 per copy

    // ---- stage tile 0 into Bt[0] ----
    int g_st[8];
#pragma unroll
    for (int c = 0; c < 8; ++c) g_st[c] = idxB[strow + c * 2];
#pragma unroll
    for (int c = 0; c < 8; ++c)
        async_copy16(SbB + ((size_t)(uint32_t)g_st[c] << 9) + goff[c],
                     (char*)&Bt[0][0] + (w * 16 + c * 2) * 512);
    // refill for tile 1
#pragma unroll
    for (int c = 0; c < 8; ++c) g_st[c] = idxB[32 + strow + c * 2];

    // ---- yv warmup: tile-0 values + tile-1 idx ----
    float yv0 = xx[idxB[lane15]];
    float yv1 = xx[idxB[16 + lane15]];
    int idx_n0 = idxB[32 + lane15];
    int idx_n1 = idxB[48 + lane15];

    // ---- A fragments: rows i0 + w*64 + si*16 + lane15, full K in regs ----
    short8 A_reg[4][8];
#pragma unroll
    for (int si = 0; si < 4; ++si) {
        const int gi = idxA[i0 + w * 64 + si * 16 + lane15];
        const char* rb = SbB + (size_t)gi * 512 + (quad << 4);
#pragma unroll
        for (int s = 0; s < 8; ++s)
            A_reg[si][s] = *(const short8*)(rb + s * 64);
    }

    // ---- LDS read offsets within a buffer (B rows lane15 / 16+lane15) ----
    int boff[8];
#pragma unroll
    for (int s = 0; s < 8; ++s)
        boff[s] = lane15 * 512 + ((((s << 2) + quad) ^ (lane15 & 7)) << 4);

    float bestv[16];
    const float binit = isNeg ? 3.4e38f : -3.4e38f;
#pragma unroll
    for (int t = 0; t < 16; ++t) bestv[t] = binit;

#pragma unroll 2
    for (int jc = 0; jc < 64; ++jc) {
        __syncthreads();   // prev readers done + this tile's loads drained

        // xx prefetch for tile jc+1 (idx loaded last iter)
        const float nv0 = xx[idx_n0];
        const float nv1 = xx[idx_n1];

        // stage tile jc+1 into the other buffer
        if (jc < 63) {
            char* lb = (char*)(&Bt[(jc + 1) & 1][0]);
#pragma unroll
            for (int c = 0; c < 8; ++c)
                async_copy16(SbB + ((size_t)(uint32_t)g_st[c] << 9) + goff[c],
                             lb + (w * 16 + c * 2) * 512);
        }
        // refills for tile jc+2 (clamped; dead on last iters)
        {
            const int nt = (jc < 62 ? jc + 2 : 63) * 32;
#pragma unroll
            for (int c = 0; c < 8; ++c) g_st[c] = idxB[nt + strow + c * 2];
            idx_n0 = idxB[nt + lane15];
            idx_n1 = idxB[nt + 16 + lane15];
        }

        // ---- compute: 8 K-steps, A regs x B LDS; 4 MFMAs per B-read ----
        const char* Bb = (const char*)(&Bt[jc & 1][0]);
        floatx4 acc[2][4];
#pragma unroll
        for (int ct = 0; ct < 2; ++ct)
#pragma unroll
            for (int si = 0; si < 4; ++si)
                acc[ct][si] = (floatx4){0.f, 0.f, 0.f, 0.f};

#pragma unroll
        for (int s = 0; s < 8; ++s) {
            short8 bf0 = *(const short8*)(Bb + boff[s]);
            short8 bf1 = *(const short8*)(Bb + boff[s] + 8192);
#pragma unroll
            for (int si = 0; si < 4; ++si)
                acc[0][si] = __builtin_amdgcn_mfma_f32_16x16x32_bf16(
                    A_reg[si][s], bf0, acc[0][si], 0, 0, 0);
#pragma unroll
            for (int si = 0; si < 4; ++si)
                acc[1][si] = __builtin_amdgcn_mfma_f32_16x16x32_bf16(
                    A_reg[si][s], bf1, acc[1][si], 0, 0, 0);
        }

        // ---- epilogue: enc = (bits(g) & ~2047) | j; single max/min ----
        const uint32_t jb0 = (uint32_t)((jc << 5) | lane15);
        const uint32_t jb1 = jb0 | 16u;
#pragma unroll
        for (int ct = 0; ct < 2; ++ct) {
            const float yv = ct ? yv1 : yv0;
            const uint32_t jb = ct ? jb1 : jb0;
#pragma unroll
            for (int si = 0; si < 4; ++si)
#pragma unroll
                for (int r = 0; r < 4; ++r) {
                    const float g = fmaf(-2.f, acc[ct][si][r], yv);
                    const float enc = __uint_as_float(
                        (__float_as_uint(g) & 0xFFFFF800u) | jb);  // v_and_or_b32
                    const int slot = si * 4 + r;
                    bestv[slot] = isNeg ? fminf(bestv[slot], enc)
                                        : fmaxf(bestv[slot], enc);
                }
        }
        yv0 = nv0; yv1 = nv1;
    }

    // ---- reduce over the 16 column-lanes (index rides in the bits) ----
#pragma unroll
    for (int slot = 0; slot < 16; ++slot) {
#pragma unroll
        for (int off = 1; off < 16; off <<= 1) {
            const float ov = __shfl_xor(bestv[slot], off);
            bestv[slot] = isNeg ? fminf(bestv[slot], ov) : fmaxf(bestv[slot], ov);
        }
    }
    if (lane15 == 0) {
#pragma unroll
        for (int si = 0; si < 4; ++si)
#pragma unroll
            for (int r = 0; r < 4; ++r) {
                const int row = w * 64 + si * 16 + quad * 4 + r;
                outIdx[i0 + row] = (int)(__float_as_uint(bestv[si * 4 + r]) & 2047u);
            }
    }
}

// ------- Kernel 3: per-anchor fp32 pdist + triplet term + global accum ------
__global__ __launch_bounds__(256) void loss_k(
        const unsigned short* __restrict__ Sb,
        const int* __restrict__ pos_idx,
        const int* __restrict__ neg_idx,
        const int* __restrict__ hp,
        const int* __restrict__ hn,
        float* __restrict__ out) {
    __shared__ float part[4];
    const int wave = threadIdx.x >> 6, lane = threadIdx.x & 63;
    const int a = blockIdx.x * 4 + wave;
    const int k = a >> 11;
    const int i = a & 2047;
    const int* pidx = pos_idx + (k << 11);
    const int* nidx = neg_idx + (k << 11);
    const int ga = pidx[i];
    const int gp = pidx[hp[a]];
    const int gn = nidx[hn[a]];

    const ushort4 va = *(const ushort4*)(Sb + (size_t)ga * C_DIM + lane * 4);
    const ushort4 vp = *(const ushort4*)(Sb + (size_t)gp * C_DIM + lane * 4);
    const ushort4 vn = *(const ushort4*)(Sb + (size_t)gn * C_DIM + lane * 4);

    float dp = 0.f, dn = 0.f;
    {
        float xa, d;
        xa = bf2f(va.x); d = xa - bf2f(vp.x); dp += d * d; d = xa - bf2f(vn.x); dn += d * d;
        xa = bf2f(va.y); d = xa - bf2f(vp.y); dp += d * d; d = xa - bf2f(vn.y); dn += d * d;
        xa = bf2f(va.z); d = xa - bf2f(vp.z); dp += d * d; d = xa - bf2f(vn.z); dn += d * d;
        xa = bf2f(va.w); d = xa - bf2f(vp.w); dp += d * d; d = xa - bf2f(vn.w); dn += d * d;
    }
#pragma unroll
    for (int off = 32; off; off >>= 1) {
        dp += __shfl_down(dp, off);
        dn += __shfl_down(dn, off);
    }
    if (lane == 0) {
        const float d_p = sqrtf(fmaxf(dp, 0.f) + EPS_D);
        const float d_n = sqrtf(fmaxf(dn, 0.f) + EPS_D);
        part[wave] = fmaxf(MARGIN_F + d_p - d_n, 0.f) * (1.0f / (float)P_POS);
    }
    __syncthreads();
    if (threadIdx.x == 0)
        atomicAdd(out, part[0] + part[1] + part[2] + part[3]);
}

extern "C" void kernel_launch(void* const* d_in, const int* in_sizes, int n_in,
                              void* d_out, int out_size, void* d_ws, size_t ws_size,
                              hipStream_t stream) {
    const float* feat    = (const float*)d_in[0];
    const int*   pos_idx = (const int*)d_in[1];
    const int*   neg_idx = (const int*)d_in[2];

    char* ws = (char*)d_ws;
    unsigned short* Sb = (unsigned short*)ws;                 // 32 MiB bf16 sigmoid
    float* xx = (float*)(ws + 33554432);                      // 256 KiB row norms
    int*   hp = (int*)  (ws + 33816576);                      // 160 KiB
    int*   hn = (int*)  (ws + 33980416);                      // 160 KiB
    float* out = (float*)d_out;

    sigmoid_norm_k<<<M_ROWS / 4, 256, 0, stream>>>(feat, Sb, xx, out);

    select_k<<<16 * 40, 128, 0, stream>>>(Sb, xx, pos_idx, neg_idx, hp, hn);

    loss_k<<<(K_CLS * P_POS) / 4, 256, 0, stream>>>(Sb, pos_idx, neg_idx, hp, hn, out);
}

// Round 7
// 250.633 us; speedup vs baseline: 1.4777x; 1.4777x over previous
//
#include <hip/hip_runtime.h>
#include <stdint.h>

#define M_ROWS 65536
#define C_DIM  256
#define K_CLS  20
#define P_POS  2048
#define MARGIN_F 0.3f
#define EPS_D (0.0001f / 256.0f)

typedef short  short8  __attribute__((ext_vector_type(8)));
typedef float  floatx4 __attribute__((ext_vector_type(4)));

__device__ __forceinline__ unsigned short f2bf(float x) {
    uint32_t u = __float_as_uint(x);
    u += 0x7fffu + ((u >> 16) & 1u);   // RNE
    return (unsigned short)(u >> 16);
}
__device__ __forceinline__ float bf2f(unsigned short h) {
    return __uint_as_float(((uint32_t)h) << 16);
}

// async 16B/lane global -> LDS (wave-uniform LDS base + lane*16)
__device__ __forceinline__ void async_copy16(const void* g, void* l) {
    __builtin_amdgcn_global_load_lds(
        (const __attribute__((address_space(1))) void*)g,
        (__attribute__((address_space(3))) void*)l, 16, 0, 0);
}

// ------- Kernel 1: sigmoid -> bf16 + fp32 row norms + hp/hn key init --------
__global__ __launch_bounds__(256) void sigmoid_norm_k(
        const float* __restrict__ feat,
        unsigned short* __restrict__ Sb,
        float* __restrict__ xx,
        unsigned int* __restrict__ hp,
        unsigned int* __restrict__ hn) {
    {   // init merge keys: hp holds argmax keys (init 0), hn argmin (init ~0)
        const int idx = blockIdx.x * 256 + threadIdx.x;
        if (idx < K_CLS * P_POS) { hp[idx] = 0u; hn[idx] = 0xFFFFFFFFu; }
    }
    const int wave = threadIdx.x >> 6, lane = threadIdx.x & 63;
    const int row = blockIdx.x * 4 + wave;
    const float4 v = *(const float4*)(feat + (size_t)row * C_DIM + lane * 4);

    unsigned short b0 = f2bf(1.f / (1.f + __expf(-v.x)));
    unsigned short b1 = f2bf(1.f / (1.f + __expf(-v.y)));
    unsigned short b2 = f2bf(1.f / (1.f + __expf(-v.z)));
    unsigned short b3 = f2bf(1.f / (1.f + __expf(-v.w)));

    ushort4 st; st.x = b0; st.y = b1; st.z = b2; st.w = b3;
    *(ushort4*)(Sb + (size_t)row * C_DIM + lane * 4) = st;

    float s0 = bf2f(b0), s1 = bf2f(b1), s2 = bf2f(b2), s3 = bf2f(b3);
    float sum = s0 * s0 + s1 * s1 + s2 * s2 + s3 * s3;
#pragma unroll
    for (int off = 32; off; off >>= 1) sum += __shfl_down(sum, off);
    if (lane == 0) xx[row] = sum;
}

// ---------------- Kernel 2: fused distance-GEMM + arg-select ----------------
// Block 256i x 32j, FOUR waves stacked in i; wave tile 64i x 32j (A 64x256 in
// regs/AGPRs -> 4 MFMAs per B-fragment LDS read). B double-buffered 2x16 KB
// via global_load_lds, XOR swizzle folded into the global source address.
// j-dimension split in 2 halves (32 tiles/block) to keep grid=640 and
// 2 blocks/CU = 8 waves/CU; partial winners merged with atomicMax/atomicMin
// on monotone-mapped float keys (index in low 11 bits). Grid 640 = 8 i-blk x
// 2 j-half x 40 (k,type); bid%40 -> same XCD per (k,type), B-set L2-resident.
__global__ __launch_bounds__(256, 2) void select_k(
        const unsigned short* __restrict__ Sb,
        const float* __restrict__ xx,
        const int* __restrict__ pos_idx,
        const int* __restrict__ neg_idx,
        unsigned int* __restrict__ hp,
        unsigned int* __restrict__ hn) {
    __shared__ __align__(16) unsigned char Bt[2][32 * 512];   // 32 KiB

    const int tid    = threadIdx.x;
    const int w      = tid >> 6;        // 0..3 (i-quarter)
    const int lane   = tid & 63;
    const int lane15 = lane & 15;
    const int quad   = lane >> 4;
    const int hi5    = lane >> 5;       // staging sub-row

    const int bid    = blockIdx.x;      // 640 = 16 (i_blk,jhalf) x 40 (k,type)
    const int ctid   = bid % 40;        // same ctid -> same XCD (mod-8)
    const int rest   = bid / 40;        // 0..15
    const int i_blk  = rest >> 1;       // 0..7
    const int jhalf  = rest & 1;        // 0..1
    const int k      = ctid >> 1;
    const int isNeg  = ctid & 1;
    const int i0     = i_blk * 256;
    const int j0     = jhalf * 1024;    // 32 tiles of 32 j

    const int* __restrict__ idxA = pos_idx + k * P_POS;
    const int* __restrict__ idxB = (isNeg ? neg_idx : pos_idx) + k * P_POS;
    unsigned int* outKey         = (isNeg ? hn : hp) + k * P_POS;

    const char* SbB = (const char*)Sb;          // row stride 512 B

    // ---- staging geometry: 4 copies x (4 waves x 2 rows) = 32 rows/tile ----
    // copy c: rows c*8 + w*2 + hi5 ; swizzled global unit = (lane&31)^(row&7)
    const int goff  = (((lane & 31) ^ ((w * 2 + hi5) & 7)) << 4);  // c*8 == 0 mod 8
    const int strow = w * 2 + hi5;      // + c*8 per copy

    // ---- stage tile 0 into Bt[0] ----
    int g_st[4];
#pragma unroll
    for (int c = 0; c < 4; ++c) g_st[c] = idxB[j0 + strow + c * 8];
#pragma unroll
    for (int c = 0; c < 4; ++c)
        async_copy16(SbB + ((size_t)(uint32_t)g_st[c] << 9) + goff,
                     (char*)&Bt[0][0] + (c * 8 + w * 2) * 512);
    // refill for tile 1
#pragma unroll
    for (int c = 0; c < 4; ++c) g_st[c] = idxB[j0 + 32 + strow + c * 8];

    // ---- yv warmup: tile-0 values + tile-1 idx ----
    float yv0 = xx[idxB[j0 + lane15]];
    float yv1 = xx[idxB[j0 + 16 + lane15]];
    int idx_n0 = idxB[j0 + 32 + lane15];
    int idx_n1 = idxB[j0 + 48 + lane15];

    // ---- A fragments: rows i0 + w*64 + si*16 + lane15, full K in regs ----
    short8 A_reg[4][8];
#pragma unroll
    for (int si = 0; si < 4; ++si) {
        const int gi = idxA[i0 + w * 64 + si * 16 + lane15];
        const char* rb = SbB + (size_t)gi * 512 + (quad << 4);
#pragma unroll
        for (int s = 0; s < 8; ++s)
            A_reg[si][s] = *(const short8*)(rb + s * 64);
    }

    // ---- LDS read offsets within a buffer (B rows lane15 / 16+lane15) ----
    int boff[8];
#pragma unroll
    for (int s = 0; s < 8; ++s)
        boff[s] = lane15 * 512 + ((((s << 2) + quad) ^ (lane15 & 7)) << 4);

    float bestv[16];
    const float binit = isNeg ? 3.4e38f : -3.4e38f;
#pragma unroll
    for (int t = 0; t < 16; ++t) bestv[t] = binit;

#pragma unroll 2
    for (int jc = 0; jc < 32; ++jc) {
        __syncthreads();   // prev readers done + this tile's loads drained

        // xx prefetch for tile jc+1 (idx loaded last iter)
        const float nv0 = xx[idx_n0];
        const float nv1 = xx[idx_n1];

        // stage tile jc+1 into the other buffer
        if (jc < 31) {
            char* lb = (char*)(&Bt[(jc + 1) & 1][0]);
#pragma unroll
            for (int c = 0; c < 4; ++c)
                async_copy16(SbB + ((size_t)(uint32_t)g_st[c] << 9) + goff,
                             lb + (c * 8 + w * 2) * 512);
        }
        // refills for tile jc+2 (clamped; dead on last iters)
        {
            const int nt = j0 + (jc < 30 ? jc + 2 : 31) * 32;
#pragma unroll
            for (int c = 0; c < 4; ++c) g_st[c] = idxB[nt + strow + c * 8];
            idx_n0 = idxB[nt + lane15];
            idx_n1 = idxB[nt + 16 + lane15];
        }

        // ---- compute: 8 K-steps, A regs x B LDS; 4 MFMAs per B-read ----
        const char* Bb = (const char*)(&Bt[jc & 1][0]);
        floatx4 acc[2][4];
#pragma unroll
        for (int ct = 0; ct < 2; ++ct)
#pragma unroll
            for (int si = 0; si < 4; ++si)
                acc[ct][si] = (floatx4){0.f, 0.f, 0.f, 0.f};

#pragma unroll
        for (int s = 0; s < 8; ++s) {
            short8 bf0 = *(const short8*)(Bb + boff[s]);
            short8 bf1 = *(const short8*)(Bb + boff[s] + 8192);
#pragma unroll
            for (int si = 0; si < 4; ++si)
                acc[0][si] = __builtin_amdgcn_mfma_f32_16x16x32_bf16(
                    A_reg[si][s], bf0, acc[0][si], 0, 0, 0);
#pragma unroll
            for (int si = 0; si < 4; ++si)
                acc[1][si] = __builtin_amdgcn_mfma_f32_16x16x32_bf16(
                    A_reg[si][s], bf1, acc[1][si], 0, 0, 0);
        }

        // ---- epilogue: enc = (bits(g) & ~2047) | j; single max/min ----
        const uint32_t jb0 = (uint32_t)((j0 + (jc << 5)) | lane15);
        const uint32_t jb1 = jb0 | 16u;
#pragma unroll
        for (int ct = 0; ct < 2; ++ct) {
            const float yv = ct ? yv1 : yv0;
            const uint32_t jb = ct ? jb1 : jb0;
#pragma unroll
            for (int si = 0; si < 4; ++si)
#pragma unroll
                for (int r = 0; r < 4; ++r) {
                    const float g = fmaf(-2.f, acc[ct][si][r], yv);
                    const float enc = __uint_as_float(
                        (__float_as_uint(g) & 0xFFFFF800u) | jb);  // v_and_or_b32
                    const int slot = si * 4 + r;
                    bestv[slot] = isNeg ? fminf(bestv[slot], enc)
                                        : fmaxf(bestv[slot], enc);
                }
        }
        yv0 = nv0; yv1 = nv1;
    }

    // ---- reduce over the 16 column-lanes (index rides in the bits) ----
#pragma unroll
    for (int slot = 0; slot < 16; ++slot) {
#pragma unroll
        for (int off = 1; off < 16; off <<= 1) {
            const float ov = __shfl_xor(bestv[slot], off);
            bestv[slot] = isNeg ? fminf(bestv[slot], ov) : fmaxf(bestv[slot], ov);
        }
    }
    // ---- merge across j-halves: monotone-mapped key + device atomics ----
    if (lane15 == 0) {
#pragma unroll
        for (int si = 0; si < 4; ++si)
#pragma unroll
            for (int r = 0; r < 4; ++r) {
                const int row = w * 64 + si * 16 + quad * 4 + r;
                const uint32_t u = __float_as_uint(bestv[si * 4 + r]);
                const uint32_t key = (u & 0x80000000u) ? ~u : (u | 0x80000000u);
                if (isNeg) atomicMin(&outKey[i0 + row], key);
                else       atomicMax(&outKey[i0 + row], key);
            }
    }
}

// ---------------- Kernel 3: per-anchor fp32 pdist + triplet term ------------
__global__ __launch_bounds__(256) void loss_k(
        const unsigned short* __restrict__ Sb,
        const int* __restrict__ pos_idx,
        const int* __restrict__ neg_idx,
        const unsigned int* __restrict__ hp,
        const unsigned int* __restrict__ hn,
        float* __restrict__ terms) {
    const int wave = threadIdx.x >> 6, lane = threadIdx.x & 63;
    const int a = blockIdx.x * 4 + wave;
    const int k = a >> 11;
    const int i = a & 2047;
    const int* pidx = pos_idx + (k << 11);
    const int* nidx = neg_idx + (k << 11);
    // decode monotone-mapped keys: bit31 set <=> original float >= 0
    const unsigned int kp = hp[a], kn = hn[a];
    const int jp = (int)((kp & 0x80000000u) ? (kp & 2047u) : ((~kp) & 2047u));
    const int jn = (int)((kn & 0x80000000u) ? (kn & 2047u) : ((~kn) & 2047u));
    const int ga = pidx[i];
    const int gp = pidx[jp];
    const int gn = nidx[jn];

    const ushort4 va = *(const ushort4*)(Sb + (size_t)ga * C_DIM + lane * 4);
    const ushort4 vp = *(const ushort4*)(Sb + (size_t)gp * C_DIM + lane * 4);
    const ushort4 vn = *(const ushort4*)(Sb + (size_t)gn * C_DIM + lane * 4);

    float dp = 0.f, dn = 0.f;
    {
        float xa, d;
        xa = bf2f(va.x); d = xa - bf2f(vp.x); dp += d * d; d = xa - bf2f(vn.x); dn += d * d;
        xa = bf2f(va.y); d = xa - bf2f(vp.y); dp += d * d; d = xa - bf2f(vn.y); dn += d * d;
        xa = bf2f(va.z); d = xa - bf2f(vp.z); dp += d * d; d = xa - bf2f(vn.z); dn += d * d;
        xa = bf2f(va.w); d = xa - bf2f(vp.w); dp += d * d; d = xa - bf2f(vn.w); dn += d * d;
    }
#pragma unroll
    for (int off = 32; off; off >>= 1) {
        dp += __shfl_down(dp, off);
        dn += __shfl_down(dn, off);
    }
    if (lane == 0) {
        float d_p = sqrtf(fmaxf(dp, 0.f) + EPS_D);
        float d_n = sqrtf(fmaxf(dn, 0.f) + EPS_D);
        terms[a] = fmaxf(MARGIN_F + d_p - d_n, 0.f);
    }
}

// ---------------- Kernel 4: final reduction (sum of class means) ------------
__global__ __launch_bounds__(1024) void reduce_k(
        const float* __restrict__ terms, float* __restrict__ out) {
    __shared__ float red[1024];
    float s = 0.f;
    for (int i = threadIdx.x; i < K_CLS * P_POS; i += 1024) s += terms[i];
    red[threadIdx.x] = s;
    __syncthreads();
    for (int off = 512; off; off >>= 1) {
        if ((int)threadIdx.x < off) red[threadIdx.x] += red[threadIdx.x + off];
        __syncthreads();
    }
    if (threadIdx.x == 0) out[0] = red[0] * (1.0f / (float)P_POS);
}

extern "C" void kernel_launch(void* const* d_in, const int* in_sizes, int n_in,
                              void* d_out, int out_size, void* d_ws, size_t ws_size,
                              hipStream_t stream) {
    const float* feat    = (const float*)d_in[0];
    const int*   pos_idx = (const int*)d_in[1];
    const int*   neg_idx = (const int*)d_in[2];

    char* ws = (char*)d_ws;
    unsigned short* Sb = (unsigned short*)ws;                 // 32 MiB bf16 sigmoid
    float*        xx = (float*)(ws + 33554432);               // 256 KiB row norms
    unsigned int* hp = (unsigned int*)(ws + 33816576);        // 160 KiB keys
    unsigned int* hn = (unsigned int*)(ws + 33980416);        // 160 KiB keys
    float*     terms = (float*)(ws + 34144256);               // 80 KiB

    sigmoid_norm_k<<<M_ROWS / 4, 256, 0, stream>>>(feat, Sb, xx, hp, hn);

    select_k<<<16 * 40, 256, 0, stream>>>(Sb, xx, pos_idx, neg_idx, hp, hn);

    loss_k<<<(K_CLS * P_POS) / 4, 256, 0, stream>>>(Sb, pos_idx, neg_idx, hp, hn, terms);

    reduce_k<<<1, 1024, 0, stream>>>(terms, (float*)d_out);
}

// Round 8
// 216.062 us; speedup vs baseline: 1.7142x; 1.1600x over previous
//
#include <hip/hip_runtime.h>
#include <stdint.h>

#define M_ROWS 65536
#define C_DIM  256
#define K_CLS  20
#define P_POS  2048
#define MARGIN_F 0.3f
#define EPS_D (0.0001f / 256.0f)

typedef float floatx4 __attribute__((ext_vector_type(4)));

// async 16B/lane global -> LDS (wave-uniform LDS base + lane*16)
__device__ __forceinline__ void async_copy16(const void* g, void* l) {
    __builtin_amdgcn_global_load_lds(
        (const __attribute__((address_space(1))) void*)g,
        (__attribute__((address_space(3))) void*)l, 16, 0, 0);
}
__device__ __forceinline__ float sigm(float x) { return 1.f / (1.f + __expf(-x)); }

// ------- Kernel 1: sigmoid -> fp8 e4m3 table + fp8-exact row norms ----------
// Also inits the hp/hn merge keys (argmax init 0, argmin init ~0).
__global__ __launch_bounds__(256) void sigmoid_norm_k(
        const float* __restrict__ feat,
        unsigned int* __restrict__ S8,     // [M][64] uint = 256 fp8/row
        float* __restrict__ xx,
        unsigned int* __restrict__ hp,
        unsigned int* __restrict__ hn) {
    {
        const int idx = blockIdx.x * 256 + threadIdx.x;
        if (idx < K_CLS * P_POS) { hp[idx] = 0u; hn[idx] = 0xFFFFFFFFu; }
    }
    const int wave = threadIdx.x >> 6, lane = threadIdx.x & 63;
    const int row = blockIdx.x * 4 + wave;
    const float4 v = *(const float4*)(feat + (size_t)row * C_DIM + lane * 4);

    const int p01 = __builtin_amdgcn_cvt_pk_fp8_f32(sigm(v.x), sigm(v.y), 0, false);
    const int p23 = __builtin_amdgcn_cvt_pk_fp8_f32(sigm(v.z), sigm(v.w), 0, false);
    const unsigned int packed = (unsigned int)(p01 & 0xFFFF) | ((unsigned int)p23 << 16);
    S8[(size_t)row * 64 + lane] = packed;

    // norms from the fp8-DECODED values (exact consistency with MFMA inputs)
    const float q0 = __builtin_amdgcn_cvt_f32_fp8(p01, 0);
    const float q1 = __builtin_amdgcn_cvt_f32_fp8(p01, 1);
    const float q2 = __builtin_amdgcn_cvt_f32_fp8(p23, 0);
    const float q3 = __builtin_amdgcn_cvt_f32_fp8(p23, 1);
    float sum = q0 * q0 + q1 * q1 + q2 * q2 + q3 * q3;
#pragma unroll
    for (int off = 32; off; off >>= 1) sum += __shfl_down(sum, off);
    if (lane == 0) xx[row] = sum;
}

// ---------------- Kernel 2: fused fp8 distance-GEMM + arg-select ------------
// Block 256i x 32j, 4 waves in i; wave tile 64i x 32j. A (64 x 256 fp8) in
// 64 regs -> 4 MFMAs per 8-B B-fragment LDS read AND ~165-reg footprint
// (2-3 waves/SIMD). B double-buffered 2 x 8 KB, global_load_lds with 16-chunk
// XOR swizzle folded into the global source address (rows are 256 B = 16
// chunks of 16 B; LDS[row][c] holds global chunk c ^ (row&15) -> conflict-
// even reads). yy pipelined in registers. Key: enc=(bits(yy-2*x.y)&~2047)|j,
// merged across j-halves via atomicMax/Min on a monotone uint mapping.
// Grid 640 = 8 i_blk x 2 j-half x 40 (k,type); bid%40 -> same XCD per
// (k,type), 512 KB fp8 B-set L2-resident.
__global__ __launch_bounds__(256, 2) void select_k(
        const unsigned int* __restrict__ S8,
        const float* __restrict__ xx,
        const int* __restrict__ pos_idx,
        const int* __restrict__ neg_idx,
        unsigned int* __restrict__ hp,
        unsigned int* __restrict__ hn) {
    __shared__ __align__(16) unsigned char Bt[2][32 * 256];   // 16 KiB

    const int tid    = threadIdx.x;
    const int w      = tid >> 6;        // 0..3 (i-quarter)
    const int lane   = tid & 63;
    const int lane15 = lane & 15;
    const int quad   = lane >> 4;

    const int bid    = blockIdx.x;      // 640 = 16 (i_blk,jhalf) x 40 (k,type)
    const int ctid   = bid % 40;
    const int rest   = bid / 40;        // 0..15
    const int i_blk  = rest >> 1;       // 0..7
    const int jhalf  = rest & 1;
    const int k      = ctid >> 1;
    const int isNeg  = ctid & 1;
    const int i0     = i_blk * 256;
    const int j0     = jhalf * 1024;    // 32 tiles of 32 j

    const int* __restrict__ idxA = pos_idx + k * P_POS;
    const int* __restrict__ idxB = (isNeg ? neg_idx : pos_idx) + k * P_POS;
    unsigned int* outKey         = (isNeg ? hn : hp) + k * P_POS;

    const char* S8B = (const char*)S8;          // row stride 256 B

    // ---- staging geometry: 8 ops/tile (2 per wave), 4 rows per op ----
    // op c of wave w covers tile-rows (w*2+c)*4 + (lane>>4); lane chunk lane&15.
    const int rl  = lane >> 4;          // 0..3
    const int cch = lane & 15;
    int rloc[2], soff[2];
#pragma unroll
    for (int c = 0; c < 2; ++c) {
        rloc[c] = (w * 2 + c) * 4 + rl;                  // tile-local row
        soff[c] = (cch ^ (rloc[c] & 15)) << 4;           // swizzled source chunk
    }

    // ---- stage tile 0 into Bt[0] ----
    int g_st[2];
#pragma unroll
    for (int c = 0; c < 2; ++c) g_st[c] = idxB[j0 + rloc[c]];
#pragma unroll
    for (int c = 0; c < 2; ++c)
        async_copy16(S8B + ((size_t)(uint32_t)g_st[c] << 8) + soff[c],
                     (char*)&Bt[0][0] + (w * 2 + c) * 1024);
    // refill for tile 1
#pragma unroll
    for (int c = 0; c < 2; ++c) g_st[c] = idxB[j0 + 32 + rloc[c]];

    // ---- yv warmup: tile-0 values + tile-1 idx ----
    float yv0 = xx[idxB[j0 + lane15]];
    float yv1 = xx[idxB[j0 + 16 + lane15]];
    int idx_n0 = idxB[j0 + 32 + lane15];
    int idx_n1 = idxB[j0 + 48 + lane15];

    // ---- A fragments: rows i0 + w*64 + si*16 + lane15, full K (fp8) ----
    long long A_reg[4][8];
#pragma unroll
    for (int si = 0; si < 4; ++si) {
        const int gi = idxA[i0 + w * 64 + si * 16 + lane15];
        const char* rb = S8B + ((size_t)(uint32_t)gi << 8) + quad * 8;
#pragma unroll
        for (int s = 0; s < 8; ++s)
            A_reg[si][s] = *(const long long*)(rb + s * 32);
    }

    // ---- LDS read offsets: row lane15, chunk (2s + q>>1)^lane15, +8 if q&1
    int boff[8];
#pragma unroll
    for (int s = 0; s < 8; ++s)
        boff[s] = lane15 * 256 + (((2 * s + (quad >> 1)) ^ lane15) << 4) +
                  (quad & 1) * 8;

    float bestv[16];
    const float binit = isNeg ? 3.4e38f : -3.4e38f;
#pragma unroll
    for (int t = 0; t < 16; ++t) bestv[t] = binit;

#pragma unroll 2
    for (int jc = 0; jc < 32; ++jc) {
        __syncthreads();   // prev readers done + this tile's loads drained

        const float nv0 = xx[idx_n0];
        const float nv1 = xx[idx_n1];

        // stage tile jc+1 into the other buffer
        if (jc < 31) {
            char* lb = (char*)(&Bt[(jc + 1) & 1][0]);
#pragma unroll
            for (int c = 0; c < 2; ++c)
                async_copy16(S8B + ((size_t)(uint32_t)g_st[c] << 8) + soff[c],
                             lb + (w * 2 + c) * 1024);
        }
        // refills for tile jc+2 (clamped; dead on last iters)
        {
            const int nt = j0 + (jc < 30 ? jc + 2 : 31) * 32;
#pragma unroll
            for (int c = 0; c < 2; ++c) g_st[c] = idxB[nt + rloc[c]];
            idx_n0 = idxB[nt + lane15];
            idx_n1 = idxB[nt + 16 + lane15];
        }

        // ---- compute: 8 K-steps; per step 2 b64 B-reads feed 8 MFMAs ----
        const char* Bb = (const char*)(&Bt[jc & 1][0]);
        floatx4 acc[2][4];
#pragma unroll
        for (int ct = 0; ct < 2; ++ct)
#pragma unroll
            for (int si = 0; si < 4; ++si)
                acc[ct][si] = (floatx4){0.f, 0.f, 0.f, 0.f};

#pragma unroll
        for (int s = 0; s < 8; ++s) {
            const long long bf0 = *(const long long*)(Bb + boff[s]);
            const long long bf1 = *(const long long*)(Bb + boff[s] + 4096);
#pragma unroll
            for (int si = 0; si < 4; ++si)
                acc[0][si] = __builtin_amdgcn_mfma_f32_16x16x32_fp8_fp8(
                    A_reg[si][s], bf0, acc[0][si], 0, 0, 0);
#pragma unroll
            for (int si = 0; si < 4; ++si)
                acc[1][si] = __builtin_amdgcn_mfma_f32_16x16x32_fp8_fp8(
                    A_reg[si][s], bf1, acc[1][si], 0, 0, 0);
        }

        // ---- epilogue: enc = (bits(g) & ~2047) | j; single max/min ----
        const uint32_t jb0 = (uint32_t)((j0 + (jc << 5)) | lane15);
        const uint32_t jb1 = jb0 | 16u;
#pragma unroll
        for (int ct = 0; ct < 2; ++ct) {
            const float yv = ct ? yv1 : yv0;
            const uint32_t jb = ct ? jb1 : jb0;
#pragma unroll
            for (int si = 0; si < 4; ++si)
#pragma unroll
                for (int r = 0; r < 4; ++r) {
                    const float g = fmaf(-2.f, acc[ct][si][r], yv);
                    const float enc = __uint_as_float(
                        (__float_as_uint(g) & 0xFFFFF800u) | jb);
                    const int slot = si * 4 + r;
                    bestv[slot] = isNeg ? fminf(bestv[slot], enc)
                                        : fmaxf(bestv[slot], enc);
                }
        }
        yv0 = nv0; yv1 = nv1;
    }

    // ---- reduce over the 16 column-lanes (index rides in the bits) ----
#pragma unroll
    for (int slot = 0; slot < 16; ++slot) {
#pragma unroll
        for (int off = 1; off < 16; off <<= 1) {
            const float ov = __shfl_xor(bestv[slot], off);
            bestv[slot] = isNeg ? fminf(bestv[slot], ov) : fmaxf(bestv[slot], ov);
        }
    }
    // ---- merge across j-halves: monotone-mapped key + device atomics ----
    if (lane15 == 0) {
#pragma unroll
        for (int si = 0; si < 4; ++si)
#pragma unroll
            for (int r = 0; r < 4; ++r) {
                const int row = w * 64 + si * 16 + quad * 4 + r;
                const uint32_t u = __float_as_uint(bestv[si * 4 + r]);
                const uint32_t key = (u & 0x80000000u) ? ~u : (u | 0x80000000u);
                if (isNeg) atomicMin(&outKey[i0 + row], key);
                else       atomicMax(&outKey[i0 + row], key);
            }
    }
}

// ------- Kernel 3: per-anchor EXACT fp32 pdist (sigmoid on the fly) ---------
__global__ __launch_bounds__(256) void loss_k(
        const float* __restrict__ feat,
        const int* __restrict__ pos_idx,
        const int* __restrict__ neg_idx,
        const unsigned int* __restrict__ hp,
        const unsigned int* __restrict__ hn,
        float* __restrict__ terms) {
    const int wave = threadIdx.x >> 6, lane = threadIdx.x & 63;
    const int a = blockIdx.x * 4 + wave;
    const int k = a >> 11;
    const int i = a & 2047;
    const int* pidx = pos_idx + (k << 11);
    const int* nidx = neg_idx + (k << 11);
    // decode monotone-mapped keys: bit31 set <=> original float >= 0
    const unsigned int kp = hp[a], kn = hn[a];
    const int jp = (int)((kp & 0x80000000u) ? (kp & 2047u) : ((~kp) & 2047u));
    const int jn = (int)((kn & 0x80000000u) ? (kn & 2047u) : ((~kn) & 2047u));
    const int ga = pidx[i];
    const int gp = pidx[jp];
    const int gn = nidx[jn];

    const float4 va = *(const float4*)(feat + (size_t)ga * C_DIM + lane * 4);
    const float4 vp = *(const float4*)(feat + (size_t)gp * C_DIM + lane * 4);
    const float4 vn = *(const float4*)(feat + (size_t)gn * C_DIM + lane * 4);

    float dp = 0.f, dn = 0.f;
    {
        float xa, d;
        xa = sigm(va.x); d = xa - sigm(vp.x); dp += d * d; d = xa - sigm(vn.x); dn += d * d;
        xa = sigm(va.y); d = xa - sigm(vp.y); dp += d * d; d = xa - sigm(vn.y); dn += d * d;
        xa = sigm(va.z); d = xa - sigm(vp.z); dp += d * d; d = xa - sigm(vn.z); dn += d * d;
        xa = sigm(va.w); d = xa - sigm(vp.w); dp += d * d; d = xa - sigm(vn.w); dn += d * d;
    }
#pragma unroll
    for (int off = 32; off; off >>= 1) {
        dp += __shfl_down(dp, off);
        dn += __shfl_down(dn, off);
    }
    if (lane == 0) {
        const float d_p = sqrtf(fmaxf(dp, 0.f) + EPS_D);
        const float d_n = sqrtf(fmaxf(dn, 0.f) + EPS_D);
        terms[a] = fmaxf(MARGIN_F + d_p - d_n, 0.f);
    }
}

// ---------------- Kernel 4: final reduction (sum of class means) ------------
__global__ __launch_bounds__(1024) void reduce_k(
        const float* __restrict__ terms, float* __restrict__ out) {
    __shared__ float red[1024];
    float s = 0.f;
    for (int i = threadIdx.x; i < K_CLS * P_POS; i += 1024) s += terms[i];
    red[threadIdx.x] = s;
    __syncthreads();
    for (int off = 512; off; off >>= 1) {
        if ((int)threadIdx.x < off) red[threadIdx.x] += red[threadIdx.x + off];
        __syncthreads();
    }
    if (threadIdx.x == 0) out[0] = red[0] * (1.0f / (float)P_POS);
}

extern "C" void kernel_launch(void* const* d_in, const int* in_sizes, int n_in,
                              void* d_out, int out_size, void* d_ws, size_t ws_size,
                              hipStream_t stream) {
    const float* feat    = (const float*)d_in[0];
    const int*   pos_idx = (const int*)d_in[1];
    const int*   neg_idx = (const int*)d_in[2];

    char* ws = (char*)d_ws;
    unsigned int* S8 = (unsigned int*)ws;                     // 16 MiB fp8 table
    float*        xx = (float*)(ws + 16777216);               // 256 KiB norms
    unsigned int* hp = (unsigned int*)(ws + 17039360);        // 160 KiB keys
    unsigned int* hn = (unsigned int*)(ws + 17203200);        // 160 KiB keys
    float*     terms = (float*)(ws + 17367040);               // 160 KiB

    sigmoid_norm_k<<<M_ROWS / 4, 256, 0, stream>>>(feat, S8, xx, hp, hn);

    select_k<<<16 * 40, 256, 0, stream>>>(S8, xx, pos_idx, neg_idx, hp, hn);

    loss_k<<<(K_CLS * P_POS) / 4, 256, 0, stream>>>(feat, pos_idx, neg_idx, hp, hn, terms);

    reduce_k<<<1, 1024, 0, stream>>>(terms, (float*)d_out);
}

// Round 10
// 187.915 us; speedup vs baseline: 1.9709x; 1.1498x over previous
//
#include <hip/hip_runtime.h>
#include <stdint.h>

#define M_ROWS 65536
#define C_DIM  256
#define K_CLS  20
#define P_POS  2048
#define MARGIN_F 0.3f
#define EPS_D (0.0001f / 256.0f)
#define SCALE1 0x7F7F7F7Fu   /* e8m0 127 = 2^0 in all four bytes */

typedef float floatx4 __attribute__((ext_vector_type(4)));
typedef int   intx8   __attribute__((ext_vector_type(8)));
union Frag8 { intx8 v; uint4 q[2]; };

// async 16B/lane global -> LDS (wave-uniform LDS base + lane*16)
__device__ __forceinline__ void async_copy16(const void* g, void* l) {
    __builtin_amdgcn_global_load_lds(
        (const __attribute__((address_space(1))) void*)g,
        (__attribute__((address_space(3))) void*)l, 16, 0, 0);
}
__device__ __forceinline__ float sigm(float x) { return 1.f / (1.f + __expf(-x)); }

// ------- Kernel 1: sigmoid -> fp8 e4m3 table + fp8-exact row norms ----------
__global__ __launch_bounds__(256) void sigmoid_norm_k(
        const float* __restrict__ feat,
        unsigned int* __restrict__ S8,     // [M][64] uint = 256 fp8/row
        float* __restrict__ xx,
        unsigned int* __restrict__ hp,
        unsigned int* __restrict__ hn) {
    {
        const int idx = blockIdx.x * 256 + threadIdx.x;
        if (idx < K_CLS * P_POS) { hp[idx] = 0u; hn[idx] = 0xFFFFFFFFu; }
    }
    const int wave = threadIdx.x >> 6, lane = threadIdx.x & 63;
    const int row = blockIdx.x * 4 + wave;
    const float4 v = *(const float4*)(feat + (size_t)row * C_DIM + lane * 4);

    const int p01 = __builtin_amdgcn_cvt_pk_fp8_f32(sigm(v.x), sigm(v.y), 0, false);
    const int p23 = __builtin_amdgcn_cvt_pk_fp8_f32(sigm(v.z), sigm(v.w), 0, false);
    const unsigned int packed = (unsigned int)(p01 & 0xFFFF) | ((unsigned int)p23 << 16);
    S8[(size_t)row * 64 + lane] = packed;

    const float q0 = __builtin_amdgcn_cvt_f32_fp8(p01, 0);
    const float q1 = __builtin_amdgcn_cvt_f32_fp8(p01, 1);
    const float q2 = __builtin_amdgcn_cvt_f32_fp8(p23, 0);
    const float q3 = __builtin_amdgcn_cvt_f32_fp8(p23, 1);
    float sum = q0 * q0 + q1 * q1 + q2 * q2 + q3 * q3;
#pragma unroll
    for (int off = 32; off; off >>= 1) sum += __shfl_down(sum, off);
    if (lane == 0) xx[row] = sum;
}

// ---------- Kernel 2: fused MX-fp8 (K=128) distance-GEMM + arg-select -------
// Block 256i x 32j, 4 waves in i; wave tile 64i x 32j. MFMA =
// mfma_scale_f32_16x16x128_f8f6f4 with unit scales (2x rate vs 16x16x32).
// A (64 x 256 fp8) in 64 VGPRs; fragment = 32 consecutive K-bytes at
// k0 = quad*32 + s*128. B double-buffered 2 x 8 KB via global_load_lds with
// 16B-chunk XOR swizzle in the global source address; fragments read as two
// independently-swizzled b128 chunks. Key: enc=(bits(yy-2*x.y)&~2047)|j,
// merged across j-halves via atomicMax/Min on monotone uint keys.
// Grid 640 = 8 i_blk x 2 j-half x 40 (k,type); bid%40 -> same XCD.
__global__ __launch_bounds__(256, 2) void select_k(
        const unsigned int* __restrict__ S8,
        const float* __restrict__ xx,
        const int* __restrict__ pos_idx,
        const int* __restrict__ neg_idx,
        unsigned int* __restrict__ hp,
        unsigned int* __restrict__ hn) {
    __shared__ __align__(16) unsigned char Bt[2][32 * 256];   // 16 KiB

    const int tid    = threadIdx.x;
    const int w      = tid >> 6;        // 0..3 (i-quarter)
    const int lane   = tid & 63;
    const int lane15 = lane & 15;
    const int quad   = lane >> 4;

    const int bid    = blockIdx.x;      // 640 = 16 (i_blk,jhalf) x 40 (k,type)
    const int ctid   = bid % 40;
    const int rest   = bid / 40;        // 0..15
    const int i_blk  = rest >> 1;       // 0..7
    const int jhalf  = rest & 1;
    const int k      = ctid >> 1;
    const int isNeg  = ctid & 1;
    const int i0     = i_blk * 256;
    const int j0     = jhalf * 1024;    // 32 tiles of 32 j

    const int* __restrict__ idxA = pos_idx + k * P_POS;
    const int* __restrict__ idxB = (isNeg ? neg_idx : pos_idx) + k * P_POS;
    unsigned int* outKey         = (isNeg ? hn : hp) + k * P_POS;

    const char* S8B = (const char*)S8;          // row stride 256 B

    // ---- staging geometry: 8 ops/tile (2 per wave), 4 rows per op ----
    const int rl  = lane >> 4;          // 0..3
    const int cch = lane & 15;
    int rloc[2], soff[2];
#pragma unroll
    for (int c = 0; c < 2; ++c) {
        rloc[c] = (w * 2 + c) * 4 + rl;                  // tile-local row
        soff[c] = (cch ^ (rloc[c] & 15)) << 4;           // swizzled source chunk
    }

    // ---- stage tile 0 into Bt[0] ----
    int g_st[2];
#pragma unroll
    for (int c = 0; c < 2; ++c) g_st[c] = idxB[j0 + rloc[c]];
#pragma unroll
    for (int c = 0; c < 2; ++c)
        async_copy16(S8B + ((size_t)(uint32_t)g_st[c] << 8) + soff[c],
                     (char*)&Bt[0][0] + (w * 2 + c) * 1024);
#pragma unroll
    for (int c = 0; c < 2; ++c) g_st[c] = idxB[j0 + 32 + rloc[c]];

    // ---- yv warmup: tile-0 values + tile-1 idx ----
    float yv0 = xx[idxB[j0 + lane15]];
    float yv1 = xx[idxB[j0 + 16 + lane15]];
    int idx_n0 = idxB[j0 + 32 + lane15];
    int idx_n1 = idxB[j0 + 48 + lane15];

    // ---- A fragments: row i0+w*64+si*16+lane15, k0 = quad*32 + s*128 ----
    Frag8 A_reg[4][2];
#pragma unroll
    for (int si = 0; si < 4; ++si) {
        const int gi = idxA[i0 + w * 64 + si * 16 + lane15];
        const char* rb = S8B + ((size_t)(uint32_t)gi << 8) + quad * 32;
#pragma unroll
        for (int s = 0; s < 2; ++s) {
            A_reg[si][s].q[0] = *(const uint4*)(rb + s * 128);
            A_reg[si][s].q[1] = *(const uint4*)(rb + s * 128 + 16);
        }
    }

    // ---- LDS read offsets: global chunks c0 = s*8 + quad*2, c0+1;
    //      LDS position = chunk ^ (row & 15) = chunk ^ lane15 ----
    int blo[2], bhi[2];
#pragma unroll
    for (int s = 0; s < 2; ++s) {
        const int c0 = s * 8 + quad * 2;
        blo[s] = lane15 * 256 + ((c0 ^ lane15) << 4);
        bhi[s] = lane15 * 256 + (((c0 + 1) ^ lane15) << 4);
    }

    float bestv[16];
    const float binit = isNeg ? 3.4e38f : -3.4e38f;
#pragma unroll
    for (int t = 0; t < 16; ++t) bestv[t] = binit;

#pragma unroll 2
    for (int jc = 0; jc < 32; ++jc) {
        __syncthreads();   // prev readers done + this tile's loads drained

        const float nv0 = xx[idx_n0];
        const float nv1 = xx[idx_n1];

        // stage tile jc+1 into the other buffer
        if (jc < 31) {
            char* lb = (char*)(&Bt[(jc + 1) & 1][0]);
#pragma unroll
            for (int c = 0; c < 2; ++c)
                async_copy16(S8B + ((size_t)(uint32_t)g_st[c] << 8) + soff[c],
                             lb + (w * 2 + c) * 1024);
        }
        // refills for tile jc+2 (clamped; dead on last iters)
        {
            const int nt = j0 + (jc < 30 ? jc + 2 : 31) * 32;
#pragma unroll
            for (int c = 0; c < 2; ++c) g_st[c] = idxB[nt + rloc[c]];
            idx_n0 = idxB[nt + lane15];
            idx_n1 = idxB[nt + 16 + lane15];
        }

        // ---- compute: 2 K-steps of 128; 4 b128 B-reads feed 8 MFMAs ----
        const char* Bb = (const char*)(&Bt[jc & 1][0]);
        floatx4 acc[2][4];
#pragma unroll
        for (int ct = 0; ct < 2; ++ct)
#pragma unroll
            for (int si = 0; si < 4; ++si)
                acc[ct][si] = (floatx4){0.f, 0.f, 0.f, 0.f};

#pragma unroll
        for (int s = 0; s < 2; ++s) {
            Frag8 bf0, bf1;
            bf0.q[0] = *(const uint4*)(Bb + blo[s]);
            bf0.q[1] = *(const uint4*)(Bb + bhi[s]);
            bf1.q[0] = *(const uint4*)(Bb + blo[s] + 4096);
            bf1.q[1] = *(const uint4*)(Bb + bhi[s] + 4096);
#pragma unroll
            for (int si = 0; si < 4; ++si)
                acc[0][si] = __builtin_amdgcn_mfma_scale_f32_16x16x128_f8f6f4(
                    A_reg[si][s].v, bf0.v, acc[0][si], 0, 0,
                    0, SCALE1, 0, SCALE1);
#pragma unroll
            for (int si = 0; si < 4; ++si)
                acc[1][si] = __builtin_amdgcn_mfma_scale_f32_16x16x128_f8f6f4(
                    A_reg[si][s].v, bf1.v, acc[1][si], 0, 0,
                    0, SCALE1, 0, SCALE1);
        }

        // ---- epilogue: enc = (bits(g) & ~2047) | j; single max/min ----
        const uint32_t jb0 = (uint32_t)((j0 + (jc << 5)) | lane15);
        const uint32_t jb1 = jb0 | 16u;
#pragma unroll
        for (int ct = 0; ct < 2; ++ct) {
            const float yv = ct ? yv1 : yv0;
            const uint32_t jb = ct ? jb1 : jb0;
#pragma unroll
            for (int si = 0; si < 4; ++si)
#pragma unroll
                for (int r = 0; r < 4; ++r) {
                    const float g = fmaf(-2.f, acc[ct][si][r], yv);
                    const float enc = __uint_as_float(
                        (__float_as_uint(g) & 0xFFFFF800u) | jb);
                    const int slot = si * 4 + r;
                    bestv[slot] = isNeg ? fminf(bestv[slot], enc)
                                        : fmaxf(bestv[slot], enc);
                }
        }
        yv0 = nv0; yv1 = nv1;
    }

    // ---- reduce over the 16 column-lanes (index rides in the bits) ----
#pragma unroll
    for (int slot = 0; slot < 16; ++slot) {
#pragma unroll
        for (int off = 1; off < 16; off <<= 1) {
            const float ov = __shfl_xor(bestv[slot], off);
            bestv[slot] = isNeg ? fminf(bestv[slot], ov) : fmaxf(bestv[slot], ov);
        }
    }
    // ---- merge across j-halves: monotone-mapped key + device atomics ----
    if (lane15 == 0) {
#pragma unroll
        for (int si = 0; si < 4; ++si)
#pragma unroll
            for (int r = 0; r < 4; ++r) {
                const int row = w * 64 + si * 16 + quad * 4 + r;
                const uint32_t u = __float_as_uint(bestv[si * 4 + r]);
                const uint32_t key = (u & 0x80000000u) ? ~u : (u | 0x80000000u);
                if (isNeg) atomicMin(&outKey[i0 + row], key);
                else       atomicMax(&outKey[i0 + row], key);
            }
    }
}

// ------- Kernel 3: per-anchor pdist from the fp8 table (fp32 math) ----------
// Consistent with selection's quantized values; 4x less gather than fp32 feat.
// NOTE: cvt_f32_fp8 byte selector MUST be a literal constant -> manual unroll.
__global__ __launch_bounds__(256) void loss_k(
        const unsigned int* __restrict__ S8,
        const int* __restrict__ pos_idx,
        const int* __restrict__ neg_idx,
        const unsigned int* __restrict__ hp,
        const unsigned int* __restrict__ hn,
        float* __restrict__ terms) {
    const int wave = threadIdx.x >> 6, lane = threadIdx.x & 63;
    const int a = blockIdx.x * 4 + wave;
    const int k = a >> 11;
    const int i = a & 2047;
    const int* pidx = pos_idx + (k << 11);
    const int* nidx = neg_idx + (k << 11);
    const unsigned int kp = hp[a], kn = hn[a];
    const int jp = (int)((kp & 0x80000000u) ? (kp & 2047u) : ((~kp) & 2047u));
    const int jn = (int)((kn & 0x80000000u) ? (kn & 2047u) : ((~kn) & 2047u));
    const int ga = pidx[i];
    const int gp = pidx[jp];
    const int gn = nidx[jn];

    const int wa = (int)S8[(size_t)ga * 64 + lane];
    const int wp = (int)S8[(size_t)gp * 64 + lane];
    const int wn = (int)S8[(size_t)gn * 64 + lane];

    float dp = 0.f, dn = 0.f;
    {
        float xa, d;
        xa = __builtin_amdgcn_cvt_f32_fp8(wa, 0);
        d = xa - __builtin_amdgcn_cvt_f32_fp8(wp, 0); dp += d * d;
        d = xa - __builtin_amdgcn_cvt_f32_fp8(wn, 0); dn += d * d;
        xa = __builtin_amdgcn_cvt_f32_fp8(wa, 1);
        d = xa - __builtin_amdgcn_cvt_f32_fp8(wp, 1); dp += d * d;
        d = xa - __builtin_amdgcn_cvt_f32_fp8(wn, 1); dn += d * d;
        xa = __builtin_amdgcn_cvt_f32_fp8(wa, 2);
        d = xa - __builtin_amdgcn_cvt_f32_fp8(wp, 2); dp += d * d;
        d = xa - __builtin_amdgcn_cvt_f32_fp8(wn, 2); dn += d * d;
        xa = __builtin_amdgcn_cvt_f32_fp8(wa, 3);
        d = xa - __builtin_amdgcn_cvt_f32_fp8(wp, 3); dp += d * d;
        d = xa - __builtin_amdgcn_cvt_f32_fp8(wn, 3); dn += d * d;
    }
#pragma unroll
    for (int off = 32; off; off >>= 1) {
        dp += __shfl_down(dp, off);
        dn += __shfl_down(dn, off);
    }
    if (lane == 0) {
        const float d_p = sqrtf(fmaxf(dp, 0.f) + EPS_D);
        const float d_n = sqrtf(fmaxf(dn, 0.f) + EPS_D);
        terms[a] = fmaxf(MARGIN_F + d_p - d_n, 0.f);
    }
}

// ---------------- Kernel 4: final reduction (sum of class means) ------------
__global__ __launch_bounds__(1024) void reduce_k(
        const float* __restrict__ terms, float* __restrict__ out) {
    __shared__ float red[1024];
    float s = 0.f;
    for (int i = threadIdx.x; i < K_CLS * P_POS; i += 1024) s += terms[i];
    red[threadIdx.x] = s;
    __syncthreads();
    for (int off = 512; off; off >>= 1) {
        if ((int)threadIdx.x < off) red[threadIdx.x] += red[threadIdx.x + off];
        __syncthreads();
    }
    if (threadIdx.x == 0) out[0] = red[0] * (1.0f / (float)P_POS);
}

extern "C" void kernel_launch(void* const* d_in, const int* in_sizes, int n_in,
                              void* d_out, int out_size, void* d_ws, size_t ws_size,
                              hipStream_t stream) {
    const float* feat    = (const float*)d_in[0];
    const int*   pos_idx = (const int*)d_in[1];
    const int*   neg_idx = (const int*)d_in[2];

    char* ws = (char*)d_ws;
    unsigned int* S8 = (unsigned int*)ws;                     // 16 MiB fp8 table
    float*        xx = (float*)(ws + 16777216);               // 256 KiB norms
    unsigned int* hp = (unsigned int*)(ws + 17039360);        // 160 KiB keys
    unsigned int* hn = (unsigned int*)(ws + 17203200);        // 160 KiB keys
    float*     terms = (float*)(ws + 17367040);               // 160 KiB

    sigmoid_norm_k<<<M_ROWS / 4, 256, 0, stream>>>(feat, S8, xx, hp, hn);

    select_k<<<16 * 40, 256, 0, stream>>>(S8, xx, pos_idx, neg_idx, hp, hn);

    loss_k<<<(K_CLS * P_POS) / 4, 256, 0, stream>>>(S8, pos_idx, neg_idx, hp, hn, terms);

    reduce_k<<<1, 1024, 0, stream>>>(terms, (float*)d_out);
}

// Round 11
// 186.354 us; speedup vs baseline: 1.9874x; 1.0084x over previous
//
#include <hip/hip_runtime.h>
#include <stdint.h>

#define M_ROWS 65536
#define C_DIM  256
#define K_CLS  20
#define P_POS  2048
#define MARGIN_F 0.3f
#define EPS_D (0.0001f / 256.0f)
#define SCALE1 0x7F7F7F7Fu   /* e8m0 127 = 2^0 in all four bytes */

typedef float floatx4 __attribute__((ext_vector_type(4)));
typedef int   intx8   __attribute__((ext_vector_type(8)));
union Frag8 { intx8 v; uint4 q[2]; };

// async 16B/lane global -> LDS (wave-uniform LDS base + lane*16)
__device__ __forceinline__ void async_copy16(const void* g, void* l) {
    __builtin_amdgcn_global_load_lds(
        (const __attribute__((address_space(1))) void*)g,
        (__attribute__((address_space(3))) void*)l, 16, 0, 0);
}
__device__ __forceinline__ float sigm(float x) { return 1.f / (1.f + __expf(-x)); }

// ------- Kernel 1: sigmoid -> fp8 e4m3 table + fp8-exact row norms ----------
__global__ __launch_bounds__(256) void sigmoid_norm_k(
        const float* __restrict__ feat,
        unsigned int* __restrict__ S8,     // [M][64] uint = 256 fp8/row
        float* __restrict__ xx,
        unsigned int* __restrict__ hp,
        unsigned int* __restrict__ hn) {
    {
        const int idx = blockIdx.x * 256 + threadIdx.x;
        if (idx < K_CLS * P_POS) { hp[idx] = 0u; hn[idx] = 0xFFFFFFFFu; }
    }
    const int wave = threadIdx.x >> 6, lane = threadIdx.x & 63;
    const int row = blockIdx.x * 4 + wave;
    const float4 v = *(const float4*)(feat + (size_t)row * C_DIM + lane * 4);

    const int p01 = __builtin_amdgcn_cvt_pk_fp8_f32(sigm(v.x), sigm(v.y), 0, false);
    const int p23 = __builtin_amdgcn_cvt_pk_fp8_f32(sigm(v.z), sigm(v.w), 0, false);
    const unsigned int packed = (unsigned int)(p01 & 0xFFFF) | ((unsigned int)p23 << 16);
    S8[(size_t)row * 64 + lane] = packed;

    const float q0 = __builtin_amdgcn_cvt_f32_fp8(p01, 0);
    const float q1 = __builtin_amdgcn_cvt_f32_fp8(p01, 1);
    const float q2 = __builtin_amdgcn_cvt_f32_fp8(p23, 0);
    const float q3 = __builtin_amdgcn_cvt_f32_fp8(p23, 1);
    float sum = q0 * q0 + q1 * q1 + q2 * q2 + q3 * q3;
#pragma unroll
    for (int off = 32; off; off >>= 1) sum += __shfl_down(sum, off);
    if (lane == 0) xx[row] = sum;
}

// ---------- Kernel 2: fused MX-fp8 (K=128) distance-GEMM + arg-select -------
// Block 256i x 32j-tile, 4 waves in i; wave tile 64i x 32j. MFMA =
// mfma_scale_f32_16x16x128_f8f6f4, unit scales. A (64 x 256 fp8) in 64 regs;
// B double-buffered 2 x 8 KB via global_load_lds with 16B-chunk XOR swizzle
// in the global source address (conflict-free: R10 SQ_LDS_BANK_CONFLICT=0).
// j split in QUARTERS (512 j = 16 tiles/block): grid 1280 = 8 i_blk x 4 jq x
// 40 (k,type) -> ~3 resident blocks/CU (158-reg unified footprint caps at
// 3 waves/SIMD; launch_bounds(256,3)), work 5/CU -> capacity stays filled.
// Key: enc=(bits(yy-2*x.y)&~2047)|j, merged across j-quarters via
// atomicMax/Min on monotone uint keys. bid%40 -> same XCD per (k,type).
__global__ __launch_bounds__(256, 3) void select_k(
        const unsigned int* __restrict__ S8,
        const float* __restrict__ xx,
        const int* __restrict__ pos_idx,
        const int* __restrict__ neg_idx,
        unsigned int* __restrict__ hp,
        unsigned int* __restrict__ hn) {
    __shared__ __align__(16) unsigned char Bt[2][32 * 256];   // 16 KiB

    const int tid    = threadIdx.x;
    const int w      = tid >> 6;        // 0..3 (i-quarter)
    const int lane   = tid & 63;
    const int lane15 = lane & 15;
    const int quad   = lane >> 4;

    const int bid    = blockIdx.x;      // 1280 = 32 (i_blk,jq) x 40 (k,type)
    const int ctid   = bid % 40;
    const int rest   = bid / 40;        // 0..31
    const int i_blk  = rest >> 2;       // 0..7
    const int jq     = rest & 3;        // 0..3
    const int k      = ctid >> 1;
    const int isNeg  = ctid & 1;
    const int i0     = i_blk * 256;
    const int j0     = jq * 512;        // 16 tiles of 32 j

    const int* __restrict__ idxA = pos_idx + k * P_POS;
    const int* __restrict__ idxB = (isNeg ? neg_idx : pos_idx) + k * P_POS;
    unsigned int* outKey         = (isNeg ? hn : hp) + k * P_POS;

    const char* S8B = (const char*)S8;          // row stride 256 B

    // ---- staging geometry: 8 ops/tile (2 per wave), 4 rows per op ----
    const int rl  = lane >> 4;          // 0..3
    const int cch = lane & 15;
    int rloc[2], soff[2];
#pragma unroll
    for (int c = 0; c < 2; ++c) {
        rloc[c] = (w * 2 + c) * 4 + rl;                  // tile-local row
        soff[c] = (cch ^ (rloc[c] & 15)) << 4;           // swizzled source chunk
    }

    // ---- stage tile 0 into Bt[0] ----
    int g_st[2];
#pragma unroll
    for (int c = 0; c < 2; ++c) g_st[c] = idxB[j0 + rloc[c]];
#pragma unroll
    for (int c = 0; c < 2; ++c)
        async_copy16(S8B + ((size_t)(uint32_t)g_st[c] << 8) + soff[c],
                     (char*)&Bt[0][0] + (w * 2 + c) * 1024);
#pragma unroll
    for (int c = 0; c < 2; ++c) g_st[c] = idxB[j0 + 32 + rloc[c]];

    // ---- yv warmup: tile-0 values + tile-1 idx ----
    float yv0 = xx[idxB[j0 + lane15]];
    float yv1 = xx[idxB[j0 + 16 + lane15]];
    int idx_n0 = idxB[j0 + 32 + lane15];
    int idx_n1 = idxB[j0 + 48 + lane15];

    // ---- A fragments: row i0+w*64+si*16+lane15, k0 = quad*32 + s*128 ----
    Frag8 A_reg[4][2];
#pragma unroll
    for (int si = 0; si < 4; ++si) {
        const int gi = idxA[i0 + w * 64 + si * 16 + lane15];
        const char* rb = S8B + ((size_t)(uint32_t)gi << 8) + quad * 32;
#pragma unroll
        for (int s = 0; s < 2; ++s) {
            A_reg[si][s].q[0] = *(const uint4*)(rb + s * 128);
            A_reg[si][s].q[1] = *(const uint4*)(rb + s * 128 + 16);
        }
    }

    // ---- LDS read offsets: global chunks c0 = s*8 + quad*2, c0+1;
    //      LDS position = chunk ^ (row & 15) = chunk ^ lane15 ----
    int blo[2], bhi[2];
#pragma unroll
    for (int s = 0; s < 2; ++s) {
        const int c0 = s * 8 + quad * 2;
        blo[s] = lane15 * 256 + ((c0 ^ lane15) << 4);
        bhi[s] = lane15 * 256 + (((c0 + 1) ^ lane15) << 4);
    }

    float bestv[16];
    const float binit = isNeg ? 3.4e38f : -3.4e38f;
#pragma unroll
    for (int t = 0; t < 16; ++t) bestv[t] = binit;

#pragma unroll 2
    for (int jc = 0; jc < 16; ++jc) {
        __syncthreads();   // prev readers done + this tile's loads drained

        const float nv0 = xx[idx_n0];
        const float nv1 = xx[idx_n1];

        // stage tile jc+1 into the other buffer
        if (jc < 15) {
            char* lb = (char*)(&Bt[(jc + 1) & 1][0]);
#pragma unroll
            for (int c = 0; c < 2; ++c)
                async_copy16(S8B + ((size_t)(uint32_t)g_st[c] << 8) + soff[c],
                             lb + (w * 2 + c) * 1024);
        }
        // refills for tile jc+2 (clamped; dead on last iters)
        {
            const int nt = j0 + (jc < 14 ? jc + 2 : 15) * 32;
#pragma unroll
            for (int c = 0; c < 2; ++c) g_st[c] = idxB[nt + rloc[c]];
            idx_n0 = idxB[nt + lane15];
            idx_n1 = idxB[nt + 16 + lane15];
        }

        // ---- compute: 2 K-steps of 128; 4 b128 B-reads feed 8 MFMAs ----
        const char* Bb = (const char*)(&Bt[jc & 1][0]);
        floatx4 acc[2][4];
#pragma unroll
        for (int ct = 0; ct < 2; ++ct)
#pragma unroll
            for (int si = 0; si < 4; ++si)
                acc[ct][si] = (floatx4){0.f, 0.f, 0.f, 0.f};

#pragma unroll
        for (int s = 0; s < 2; ++s) {
            Frag8 bf0, bf1;
            bf0.q[0] = *(const uint4*)(Bb + blo[s]);
            bf0.q[1] = *(const uint4*)(Bb + bhi[s]);
            bf1.q[0] = *(const uint4*)(Bb + blo[s] + 4096);
            bf1.q[1] = *(const uint4*)(Bb + bhi[s] + 4096);
#pragma unroll
            for (int si = 0; si < 4; ++si)
                acc[0][si] = __builtin_amdgcn_mfma_scale_f32_16x16x128_f8f6f4(
                    A_reg[si][s].v, bf0.v, acc[0][si], 0, 0,
                    0, SCALE1, 0, SCALE1);
#pragma unroll
            for (int si = 0; si < 4; ++si)
                acc[1][si] = __builtin_amdgcn_mfma_scale_f32_16x16x128_f8f6f4(
                    A_reg[si][s].v, bf1.v, acc[1][si], 0, 0,
                    0, SCALE1, 0, SCALE1);
        }

        // ---- epilogue: enc = (bits(g) & ~2047) | j; single max/min ----
        const uint32_t jb0 = (uint32_t)((j0 + (jc << 5)) | lane15);
        const uint32_t jb1 = jb0 | 16u;
#pragma unroll
        for (int ct = 0; ct < 2; ++ct) {
            const float yv = ct ? yv1 : yv0;
            const uint32_t jb = ct ? jb1 : jb0;
#pragma unroll
            for (int si = 0; si < 4; ++si)
#pragma unroll
                for (int r = 0; r < 4; ++r) {
                    const float g = fmaf(-2.f, acc[ct][si][r], yv);
                    const float enc = __uint_as_float(
                        (__float_as_uint(g) & 0xFFFFF800u) | jb);
                    const int slot = si * 4 + r;
                    bestv[slot] = isNeg ? fminf(bestv[slot], enc)
                                        : fmaxf(bestv[slot], enc);
                }
        }
        yv0 = nv0; yv1 = nv1;
    }

    // ---- reduce over the 16 column-lanes (index rides in the bits) ----
#pragma unroll
    for (int slot = 0; slot < 16; ++slot) {
#pragma unroll
        for (int off = 1; off < 16; off <<= 1) {
            const float ov = __shfl_xor(bestv[slot], off);
            bestv[slot] = isNeg ? fminf(bestv[slot], ov) : fmaxf(bestv[slot], ov);
        }
    }
    // ---- merge across j-quarters: monotone-mapped key + device atomics ----
    if (lane15 == 0) {
#pragma unroll
        for (int si = 0; si < 4; ++si)
#pragma unroll
            for (int r = 0; r < 4; ++r) {
                const int row = w * 64 + si * 16 + quad * 4 + r;
                const uint32_t u = __float_as_uint(bestv[si * 4 + r]);
                const uint32_t key = (u & 0x80000000u) ? ~u : (u | 0x80000000u);
                if (isNeg) atomicMin(&outKey[i0 + row], key);
                else       atomicMax(&outKey[i0 + row], key);
            }
    }
}

// ------- Kernel 3: per-anchor pdist from the fp8 table (fp32 math) ----------
// Consistent with selection's quantized values; cvt selectors are literals.
__global__ __launch_bounds__(256) void loss_k(
        const unsigned int* __restrict__ S8,
        const int* __restrict__ pos_idx,
        const int* __restrict__ neg_idx,
        const unsigned int* __restrict__ hp,
        const unsigned int* __restrict__ hn,
        float* __restrict__ terms) {
    const int wave = threadIdx.x >> 6, lane = threadIdx.x & 63;
    const int a = blockIdx.x * 4 + wave;
    const int k = a >> 11;
    const int i = a & 2047;
    const int* pidx = pos_idx + (k << 11);
    const int* nidx = neg_idx + (k << 11);
    const unsigned int kp = hp[a], kn = hn[a];
    const int jp = (int)((kp & 0x80000000u) ? (kp & 2047u) : ((~kp) & 2047u));
    const int jn = (int)((kn & 0x80000000u) ? (kn & 2047u) : ((~kn) & 2047u));
    const int ga = pidx[i];
    const int gp = pidx[jp];
    const int gn = nidx[jn];

    const int wa = (int)S8[(size_t)ga * 64 + lane];
    const int wp = (int)S8[(size_t)gp * 64 + lane];
    const int wn = (int)S8[(size_t)gn * 64 + lane];

    float dp = 0.f, dn = 0.f;
    {
        float xa, d;
        xa = __builtin_amdgcn_cvt_f32_fp8(wa, 0);
        d = xa - __builtin_amdgcn_cvt_f32_fp8(wp, 0); dp += d * d;
        d = xa - __builtin_amdgcn_cvt_f32_fp8(wn, 0); dn += d * d;
        xa = __builtin_amdgcn_cvt_f32_fp8(wa, 1);
        d = xa - __builtin_amdgcn_cvt_f32_fp8(wp, 1); dp += d * d;
        d = xa - __builtin_amdgcn_cvt_f32_fp8(wn, 1); dn += d * d;
        xa = __builtin_amdgcn_cvt_f32_fp8(wa, 2);
        d = xa - __builtin_amdgcn_cvt_f32_fp8(wp, 2); dp += d * d;
        d = xa - __builtin_amdgcn_cvt_f32_fp8(wn, 2); dn += d * d;
        xa = __builtin_amdgcn_cvt_f32_fp8(wa, 3);
        d = xa - __builtin_amdgcn_cvt_f32_fp8(wp, 3); dp += d * d;
        d = xa - __builtin_amdgcn_cvt_f32_fp8(wn, 3); dn += d * d;
    }
#pragma unroll
    for (int off = 32; off; off >>= 1) {
        dp += __shfl_down(dp, off);
        dn += __shfl_down(dn, off);
    }
    if (lane == 0) {
        const float d_p = sqrtf(fmaxf(dp, 0.f) + EPS_D);
        const float d_n = sqrtf(fmaxf(dn, 0.f) + EPS_D);
        terms[a] = fmaxf(MARGIN_F + d_p - d_n, 0.f);
    }
}

// ---------------- Kernel 4: final reduction (sum of class means) ------------
__global__ __launch_bounds__(1024) void reduce_k(
        const float* __restrict__ terms, float* __restrict__ out) {
    __shared__ float red[1024];
    float s = 0.f;
    for (int i = threadIdx.x; i < K_CLS * P_POS; i += 1024) s += terms[i];
    red[threadIdx.x] = s;
    __syncthreads();
    for (int off = 512; off; off >>= 1) {
        if ((int)threadIdx.x < off) red[threadIdx.x] += red[threadIdx.x + off];
        __syncthreads();
    }
    if (threadIdx.x == 0) out[0] = red[0] * (1.0f / (float)P_POS);
}

extern "C" void kernel_launch(void* const* d_in, const int* in_sizes, int n_in,
                              void* d_out, int out_size, void* d_ws, size_t ws_size,
                              hipStream_t stream) {
    const float* feat    = (const float*)d_in[0];
    const int*   pos_idx = (const int*)d_in[1];
    const int*   neg_idx = (const int*)d_in[2];

    char* ws = (char*)d_ws;
    unsigned int* S8 = (unsigned int*)ws;                     // 16 MiB fp8 table
    float*        xx = (float*)(ws + 16777216);               // 256 KiB norms
    unsigned int* hp = (unsigned int*)(ws + 17039360);        // 160 KiB keys
    unsigned int* hn = (unsigned int*)(ws + 17203200);        // 160 KiB keys
    float*     terms = (float*)(ws + 17367040);               // 160 KiB

    sigmoid_norm_k<<<M_ROWS / 4, 256, 0, stream>>>(feat, S8, xx, hp, hn);

    select_k<<<32 * 40, 256, 0, stream>>>(S8, xx, pos_idx, neg_idx, hp, hn);

    loss_k<<<(K_CLS * P_POS) / 4, 256, 0, stream>>>(S8, pos_idx, neg_idx, hp, hn, terms);

    reduce_k<<<1, 1024, 0, stream>>>(terms, (float*)d_out);
}